// Round 3
// baseline (257.228 us; speedup 1.0000x reference)
//
#include <hip/hip_runtime.h>
#include <math.h>

#define N_PTS   10000
#define CIN     64
#define COUT    32
#define KCAP    32
#define RADIUSF 0.07f
#define NCELLS  27
#define MAXC    128

__global__ __launch_bounds__(64) void cconv_fused_kernel(
    const float* __restrict__ feats,
    const float* __restrict__ points,
    const float* __restrict__ W,
    const float* __restrict__ bias,
    float* __restrict__ out)
{
    const int n    = blockIdx.x;
    const int lane = threadIdx.x;

    __shared__ float sA[NCELLS][CIN];   // 6.75 KB accumulation buffer
    __shared__ float s_d2[MAXC];
    __shared__ int   s_idx[MAXC];
    __shared__ int   s_rank[MAXC];
    __shared__ int   s_sel[KCAP];
    __shared__ int   s_cnt;

    if (lane == 0) s_cnt = 0;
    // zero A
    for (int c = lane; c < NCELLS * CIN; c += 64) ((float*)sA)[c] = 0.0f;
    __syncthreads();

    // ---- Phase 1: radius search (replicate ref d2 formula exactly) ----
    const float qx = points[3 * n + 0];
    const float qy = points[3 * n + 1];
    const float qz = points[3 * n + 2];
    const float sqn = qx * qx + qy * qy + qz * qz;
    const float r2 = RADIUSF * RADIUSF;

    for (int j = lane; j < N_PTS; j += 64) {
        float x = points[3 * j + 0];
        float y = points[3 * j + 1];
        float z = points[3 * j + 2];
        float sqj = x * x + y * y + z * z;
        float dot = qx * x + qy * y + qz * z;
        float d2 = (sqn + sqj) - 2.0f * dot;   // same form as ref: sq_i + sq_j - 2*dot
        if (d2 <= r2) {
            int pos = atomicAdd(&s_cnt, 1);
            if (pos < MAXC) { s_d2[pos] = d2; s_idx[pos] = j; }
        }
    }
    __syncthreads();

    int M = s_cnt;
    if (M > MAXC) M = MAXC;

    int cnt;
    if (M > KCAP) {
        // exact top-32 selection, tie-break by original index (lax.top_k stable order)
        for (int c = lane; c < M; c += 64) {
            float dc = s_d2[c];
            int   ic = s_idx[c];
            int rank = 0;
            for (int m = 0; m < M; ++m) {
                float dm = s_d2[m];
                int   im = s_idx[m];
                rank += (dm < dc || (dm == dc && im < ic)) ? 1 : 0;
            }
            s_rank[c] = rank;
        }
        __syncthreads();
        for (int c = lane; c < M; c += 64) {
            int r = s_rank[c];
            if (r < KCAP) s_sel[r] = s_idx[c];
        }
        __syncthreads();
        cnt = KCAP;
    } else {
        cnt = M;
    }
    const int* nbr = (M > KCAP) ? s_sel : s_idx;

    // ---- Phase 2: trilinear scatter-accumulate A[27][64] ----
    // lane = feature channel
    for (int k = 0; k < cnt; ++k) {
        int j = nbr[k];
        float x = points[3 * j + 0];
        float y = points[3 * j + 1];
        float z = points[3 * j + 2];
        float rx = (x - qx) / RADIUSF;
        float ry = (y - qy) / RADIUSF;
        float rz = (z - qz) / RADIUSF;
        float l2 = sqrtf(rx * rx + ry * ry + rz * rz);
        float ax = fabsf(rx), ay = fabsf(ry), az = fabsf(rz);
        float linf = fmaxf(fmaxf(ax, ay), az);
        float s = (linf > 0.0f) ? (l2 / fmaxf(linf, 1e-12f)) : 0.0f;
        float tx = rx * s, ty = ry * s, tz = rz * s;
        // coords = (t+1)*0.5*(KSIZE-1) = t + 1  (KSIZE=3)
        float cx = (tx + 1.0f) * 0.5f * 2.0f;
        float cy = (ty + 1.0f) * 0.5f * 2.0f;
        float cz = (tz + 1.0f) * 0.5f * 2.0f;
        float c0x = fminf(fmaxf(floorf(cx), 0.0f), 1.0f);
        float c0y = fminf(fmaxf(floorf(cy), 0.0f), 1.0f);
        float c0z = fminf(fmaxf(floorf(cz), 0.0f), 1.0f);
        float fx = cx - c0x;
        float fy = cy - c0y;
        float fz = cz - c0z;
        int i0 = (int)c0x, i1 = (int)c0y, i2 = (int)c0z;
        int base = i0 * 9 + i1 * 3 + i2;

        float gx0 = 1.0f - fx, gx1 = fx;
        float gy0 = 1.0f - fy, gy1 = fy;
        float gz0 = 1.0f - fz, gz1 = fz;

        float featv = feats[j * CIN + lane];

        // 8 corners: cell = base + oi*9 + oj*3 + ok
        sA[base + 0 ][lane] += (gx0 * gy0) * gz0 * featv;
        sA[base + 1 ][lane] += (gx0 * gy0) * gz1 * featv;
        sA[base + 3 ][lane] += (gx0 * gy1) * gz0 * featv;
        sA[base + 4 ][lane] += (gx0 * gy1) * gz1 * featv;
        sA[base + 9 ][lane] += (gx1 * gy0) * gz0 * featv;
        sA[base + 10][lane] += (gx1 * gy0) * gz1 * featv;
        sA[base + 12][lane] += (gx1 * gy1) * gz0 * featv;
        sA[base + 13][lane] += (gx1 * gy1) * gz1 * featv;
    }
    __syncthreads();

    // ---- Phase 3: out[o] = sum_{cell,f} A[cell][f] * W[cell][f][o] ----
    // lanes 0..31 handle cells 0..13, lanes 32..63 handle cells 14..26
    const int o    = lane & 31;
    const int half = lane >> 5;
    const int c_begin = half ? 14 : 0;
    const int c_end   = half ? 27 : 14;
    float acc = 0.0f;
    for (int cell = c_begin; cell < c_end; ++cell) {
        const float* __restrict__ Wrow = W + (cell * CIN) * COUT + o;
        #pragma unroll 8
        for (int f = 0; f < CIN; ++f) {
            acc += sA[cell][f] * Wrow[f * COUT];
        }
    }
    acc += __shfl_xor(acc, 32);

    if (lane < COUT) {
        float nn = (float)cnt;
        out[n * COUT + lane] = acc / fmaxf(nn, 1.0f) + bias[lane];
    }
}

extern "C" void kernel_launch(void* const* d_in, const int* in_sizes, int n_in,
                              void* d_out, int out_size, void* d_ws, size_t ws_size,
                              hipStream_t stream) {
    const float* feats  = (const float*)d_in[0];
    const float* points = (const float*)d_in[1];
    const float* W      = (const float*)d_in[2];
    const float* bias   = (const float*)d_in[3];
    float* out = (float*)d_out;

    cconv_fused_kernel<<<N_PTS, 64, 0, stream>>>(feats, points, W, bias, out);
}